// Round 1
// baseline (24.466 us; speedup 1.0000x reference)
//
#include <hip/hip_runtime.h>

// MaxRecallLoss: fused per-sample loss + deterministic 2-stage reduction.
// B = 2,097,152 samples, C = 8 classes. Cancer classes {0,1,3} -> mask 0xB.

constexpr int C = 8;
constexpr int NT = 256;   // threads per block
constexpr int NB = 2048;  // blocks in pass 1 (grid-stride)

__device__ __forceinline__ float wave_reduce_sum(float v) {
    #pragma unroll
    for (int off = 32; off > 0; off >>= 1) v += __shfl_down(v, off, 64);
    return v;
}

__global__ __launch_bounds__(NT) void mrl_pass1(
    const float* __restrict__ logits,
    const int*   __restrict__ targets,
    const float* __restrict__ counts,
    float*       __restrict__ part,   // [3*NB]: ce | tp | cnt
    int B)
{
    __shared__ float s_bw[C];
    __shared__ float s_red[(NT / 64) * 3];

    if (threadIdx.x == 0) {
        float w[C];
        float ws = 0.0f;
        #pragma unroll
        for (int c = 0; c < C; ++c) { w[c] = rsqrtf(counts[c] + 1.0f); ws += w[c]; }
        const float scale = (float)C / ws;
        #pragma unroll
        for (int c = 0; c < C; ++c) s_bw[c] = w[c] * scale;
    }
    __syncthreads();

    const float inv_temp = 1.0f / 1.5f;
    // label-smoothing constants (compiler folds; matches float32 ref arithmetic)
    const float c_uni   = 0.05f / 8.0f;          // cancer target: uniform mass
    const float c_one   = 1.0f - 0.05f;          // cancer target: one-hot mass
    const float b_uni   = 0.1f / 8.0f;           // benign target: uniform mass
    const float b_one   = 1.0f - 0.1f;           // benign target: one-hot mass
    const float b_extra = 0.1f * 0.5f / 3.0f;    // benign: extra on cancer cols
    const float b_norm  = 1.0f / (1.0f + 3.0f * (0.1f * 0.5f / 3.0f)); // 1/1.05

    float ce_sum = 0.0f, tp_sum = 0.0f, cnt_sum = 0.0f;

    const int stride = gridDim.x * blockDim.x;
    for (int i = blockIdx.x * blockDim.x + threadIdx.x; i < B; i += stride) {
        const float4* row = reinterpret_cast<const float4*>(logits + (size_t)i * 8);
        const float4 a = row[0];
        const float4 b = row[1];
        const float l[8] = {a.x, a.y, a.z, a.w, b.x, b.y, b.z, b.w};
        const int t = targets[i];

        // max + argmax (first-max tie-break, matches jnp.argmax)
        float m = l[0];
        int   p = 0;
        #pragma unroll
        for (int j = 1; j < 8; ++j) { if (l[j] > m) { m = l[j]; p = j; } }

        // temp-1 softmax pieces (for cancer prob) -- exp(l-m) <= 1, safe
        float se = 0.0f, e0, e1, e3;
        {
            float e[8];
            #pragma unroll
            for (int j = 0; j < 8; ++j) { e[j] = __expf(l[j] - m); se += e[j]; }
            e0 = e[0]; e1 = e[1]; e3 = e[3];
        }
        const float cp = (e0 + e1 + e3) / se;

        // temp-1.5 log-sum-exp:  x_j = l_j/1.5, logZ = m/1.5 + log(sum exp(x-m/1.5))
        float se2 = 0.0f;
        #pragma unroll
        for (int j = 0; j < 8; ++j) se2 += __expf((l[j] - m) * inv_temp);
        const float logZ = m * inv_temp + __logf(se2);

        // dot(smoothed_labels, x) without materializing the row
        float S = 0.0f;
        #pragma unroll
        for (int j = 0; j < 8; ++j) S += l[j];
        const float X  = S * inv_temp;                     // sum of x_j
        const float Xc = (l[0] + l[1] + l[3]) * inv_temp;  // cancer-col sum of x_j
        float lt = l[0];
        #pragma unroll
        for (int j = 1; j < 8; ++j) lt = (t == j) ? l[j] : lt;
        const float xt = lt * inv_temp;

        const bool isct = ((1u << t) & 0xBu) != 0u;  // target in {0,1,3}
        const bool iscp = ((1u << p) & 0xBu) != 0u;  // pred   in {0,1,3}

        float dot;
        if (isct) dot = c_uni * X + c_one * xt;
        else      dot = (b_uni * X + b_one * xt + b_extra * Xc) * b_norm;

        float ce = (logZ - dot) * s_bw[t];

        // FN multipliers (where-order: MEL override wins)
        float mult = (isct && !iscp) ? 3.0f : 1.0f;
        if (t == 0 && !iscp) mult = 5.0f;
        // hard mining
        if (isct && p != t) mult *= 2.0f;
        ce *= mult;

        ce_sum += ce;
        if (isct) { tp_sum += cp; cnt_sum += 1.0f; }
    }

    // block reduction (fixed order -> deterministic)
    float v0 = wave_reduce_sum(ce_sum);
    float v1 = wave_reduce_sum(tp_sum);
    float v2 = wave_reduce_sum(cnt_sum);
    const int lane = threadIdx.x & 63;
    const int wid  = threadIdx.x >> 6;
    if (lane == 0) {
        s_red[wid * 3 + 0] = v0;
        s_red[wid * 3 + 1] = v1;
        s_red[wid * 3 + 2] = v2;
    }
    __syncthreads();
    if (threadIdx.x == 0) {
        float r0 = 0.0f, r1 = 0.0f, r2 = 0.0f;
        #pragma unroll
        for (int w = 0; w < NT / 64; ++w) {
            r0 += s_red[w * 3 + 0];
            r1 += s_red[w * 3 + 1];
            r2 += s_red[w * 3 + 2];
        }
        part[blockIdx.x]          = r0;
        part[NB + blockIdx.x]     = r1;
        part[2 * NB + blockIdx.x] = r2;
    }
}

__global__ __launch_bounds__(NT) void mrl_pass2(
    const float* __restrict__ part,
    float*       __restrict__ out,
    int B)
{
    __shared__ float s_red[(NT / 64) * 3];

    float ce = 0.0f, tp = 0.0f, cnt = 0.0f;
    for (int k = threadIdx.x; k < NB; k += NT) {
        ce  += part[k];
        tp  += part[NB + k];
        cnt += part[2 * NB + k];
    }
    float v0 = wave_reduce_sum(ce);
    float v1 = wave_reduce_sum(tp);
    float v2 = wave_reduce_sum(cnt);
    const int lane = threadIdx.x & 63;
    const int wid  = threadIdx.x >> 6;
    if (lane == 0) {
        s_red[wid * 3 + 0] = v0;
        s_red[wid * 3 + 1] = v1;
        s_red[wid * 3 + 2] = v2;
    }
    __syncthreads();
    if (threadIdx.x == 0) {
        float r0 = 0.0f, r1 = 0.0f, r2 = 0.0f;
        #pragma unroll
        for (int w = 0; w < NT / 64; ++w) {
            r0 += s_red[w * 3 + 0];
            r1 += s_red[w * 3 + 1];
            r2 += s_red[w * 3 + 2];
        }
        const float base_loss   = r0 / (float)B;
        const float recall_loss = 1.0f - r1 / (r2 + 1e-8f);
        out[0] = base_loss + 0.5f * recall_loss;
    }
}

extern "C" void kernel_launch(void* const* d_in, const int* in_sizes, int n_in,
                              void* d_out, int out_size, void* d_ws, size_t ws_size,
                              hipStream_t stream) {
    const float* logits  = (const float*)d_in[0];
    const int*   targets = (const int*)d_in[1];
    const float* counts  = (const float*)d_in[2];
    float* out  = (float*)d_out;
    float* part = (float*)d_ws;   // 3*NB floats = 24 KB scratch
    const int B = in_sizes[1];    // targets element count

    mrl_pass1<<<NB, NT, 0, stream>>>(logits, targets, counts, part, B);
    mrl_pass2<<<1, NT, 0, stream>>>(part, out, B);
}